// Round 11
// baseline (222.215 us; speedup 1.0000x reference)
//
#include <hip/hip_runtime.h>
#include <hip/hip_bf16.h>
#include <hip/hip_fp16.h>

// GCN link-prediction: 2x GCNConv + dot decoder. N=50000, F_in=50, H=50, D=64,
// E_train=1.6M, Ep=En=200k.
//
// R25 fix-resubmit (R25 never ran: __builtin_nontemporal_* rejects
// HIP_vector_type uint4/float4; now wrapped via clang ext_vector_type(4)
// helpers -> still a single non-temporal dwordx4).
// Synthesis of R18/R20/R23/R24: aggs are L2-MISS-LATENCY bound, not HBM-BW
// bound (fetch halving didn't help; instr halving didn't help). R23's
// FETCH=87MB == demand bytes -> ZERO L2 reuse in every variant: in-kernel
// phase splits never bound the INSTANTANEOUS working set because waves drift.
// R25: bound it with a LAUNCH boundary. Each agg pass = two kernels:
//   phase A: per node, gather tile-0..3 edges (source rows 0..24999 = 3.2MB,
//            fits 4MB per-XCD L2) + self-loop if node<25000 -> fp32 partial.
//   phase B: reload partial (+self if node>=25000), gather tiles 4..7
//            (rows 25000..49999), finalize (mm2 / bias+pack).
// Gather loop = R21's proven uint4 form generalized to [jlo,jhi) with masked
// head/tail batches (masked lanes -> row 0, keeps window pure). Streaming
// traffic (srcIdx, partials, outputs) is NON-TEMPORAL so it can't evict the
// row window. bucket_csr emits dlo[node] = deg in tiles 0-3 (u8).
// Accum order preserved for node<25000; self moves to mid-list for >=25000
// (fp32 reorder only; R19/R21 reorders passed at identical absmax).
// Carried: R21 sorted-coalesced partition, R19 ticketed bucket_csr @512,
// R17 CHUNK 6144 / NTILE 8 / fp16 buffers / 8-lane decode.

constexpr int N_NODES = 50000;
constexpr int NBITS = 6;                          // 64 nodes per bucket
constexpr int BNODES = 1 << NBITS;                // 64
constexpr int NBUCK = (N_NODES + BNODES - 1) / BNODES;  // 782
constexpr int CAP = 2560;     // per-bucket capacity incl. 8-align pad (6.4 sigma)
constexpr int CHUNK = 6144;   // edges per partition block (261 blocks)
constexpr int PTHREADS = 512; // partition block size (8 waves)
constexpr int CTHREADS = 512; // bucket_csr_mm block size (8 waves)
constexpr int NTILE = 8;
constexpr int TROWS = 6250;   // rows per tile (8 tiles cover 50000)
constexpr int SPLIT_ROW = 4 * TROWS;  // 25000: tiles 0-3 vs 4-7 boundary

typedef unsigned int u32x4 __attribute__((ext_vector_type(4)));
typedef float f32x4 __attribute__((ext_vector_type(4)));

__device__ inline uint4 ntload_u4(const uint4* p) {
    u32x4 v = __builtin_nontemporal_load((const u32x4*)p);
    return make_uint4(v.x, v.y, v.z, v.w);
}

__device__ inline void ntstore_u4(uint4* p, uint4 v) {
    u32x4 t = {v.x, v.y, v.z, v.w};
    __builtin_nontemporal_store(t, (u32x4*)p);
}

__device__ inline float4 ntload_f4(const float4* p) {
    f32x4 v = __builtin_nontemporal_load((const f32x4*)p);
    return make_float4(v.x, v.y, v.z, v.w);
}

__device__ inline void ntstore_f4(float4* p, float4 v) {
    f32x4 t = {v.x, v.y, v.z, v.w};
    __builtin_nontemporal_store(t, (f32x4*)p);
}

union H4 {  // 4 fp16 = 8 bytes = one uint2 load/store
    uint2 u;
    __half2 h[2];
};

union H8 {  // 8 fp16 = 16 bytes = one uint4 load/store
    uint4 u;
    __half2 h[4];
};

__device__ inline H4 f4_to_h4(float4 v) {
    H4 r;
    r.h[0] = __floats2half2_rn(v.x, v.y);
    r.h[1] = __floats2half2_rn(v.z, v.w);
    return r;
}

__device__ inline uint4 pack8(float4 A, float4 B) {
    H8 r;
    r.h[0] = __floats2half2_rn(A.x, A.y);
    r.h[1] = __floats2half2_rn(A.z, A.w);
    r.h[2] = __floats2half2_rn(B.x, B.y);
    r.h[3] = __floats2half2_rn(B.z, B.w);
    return r.u;
}

__device__ inline void unpack8(uint4 w, int* r) {
    r[0] = (int)(w.x & 0xffffu);  r[1] = (int)(w.x >> 16);
    r[2] = (int)(w.y & 0xffffu);  r[3] = (int)(w.y >> 16);
    r[4] = (int)(w.z & 0xffffu);  r[5] = (int)(w.z >> 16);
    r[6] = (int)(w.w & 0xffffu);  r[7] = (int)(w.w >> 16);
}

__device__ inline void add8(float4& A, float4& B, H8 v) {
    float2 g0 = __half22float2(v.h[0]);
    float2 g1 = __half22float2(v.h[1]);
    float2 g2 = __half22float2(v.h[2]);
    float2 g3 = __half22float2(v.h[3]);
    A.x += g0.x; A.y += g0.y; A.z += g1.x; A.w += g1.y;
    B.x += g2.x; B.y += g2.y; B.z += g3.x; B.w += g3.y;
}

__device__ inline void fma8(float4& A, float4& B, H8 v, float m) {
    float2 g0 = __half22float2(v.h[0]);
    float2 g1 = __half22float2(v.h[1]);
    float2 g2 = __half22float2(v.h[2]);
    float2 g3 = __half22float2(v.h[3]);
    A.x = fmaf(m, g0.x, A.x); A.y = fmaf(m, g0.y, A.y);
    A.z = fmaf(m, g1.x, A.z); A.w = fmaf(m, g1.y, A.w);
    B.x = fmaf(m, g2.x, B.x); B.y = fmaf(m, g2.y, B.y);
    B.z = fmaf(m, g3.x, B.z); B.w = fmaf(m, g3.y, B.w);
}

__device__ inline float hdot2(unsigned ua, unsigned ub) {
    __half2 ha = *(__half2*)&ua;
    __half2 hb = *(__half2*)&ub;
    float2 fa = __half22float2(ha);
    float2 fb = __half22float2(hb);
    return fa.x * fb.x + fa.y * fb.y;
}

// Pass 1: bucket edges by target, block-locally SORTED by bucket before the
// global write so consecutive lanes write consecutive addresses per bucket
// run (coalesced). Packed edge = (row<<16)|col (both < 65536).
__global__ __launch_bounds__(PTHREADS) void partition_kernel(const int4* __restrict__ row4,
                                                             const int4* __restrict__ col4, int E,
                                                             int* __restrict__ cursor,
                                                             unsigned* __restrict__ bEdges) {
    __shared__ unsigned ed2[CHUNK];        // 24 KB: bucket-sorted edges
    __shared__ unsigned char tick[CHUNK];  //  6 KB: rank within (block,bucket)
    __shared__ int cnt[NBUCK];             // 3.1 KB
    __shared__ int loff[NBUCK];            // 3.1 KB: local sorted segment start
    __shared__ int base[NBUCK];            // 3.1 KB: global segment start
    int t = threadIdx.x;
    int e0 = blockIdx.x * CHUNK;
    int n = min(CHUNK, E - e0);  // multiple of 4
    int n4 = n >> 2;
    for (int i = t; i < NBUCK; i += PTHREADS) cnt[i] = 0;
    __syncthreads();
    const int4* r4 = row4 + (e0 >> 2);
    const int4* c4 = col4 + (e0 >> 2);
    // pass A: histogram + tickets (cols only; edges re-read L2-hot in pass B)
    for (int i = t; i < n4; i += PTHREADS) {
        int4 c = c4[i];
        tick[i * 4 + 0] = (unsigned char)atomicAdd(&cnt[c.x >> NBITS], 1);
        tick[i * 4 + 1] = (unsigned char)atomicAdd(&cnt[c.y >> NBITS], 1);
        tick[i * 4 + 2] = (unsigned char)atomicAdd(&cnt[c.z >> NBITS], 1);
        tick[i * 4 + 3] = (unsigned char)atomicAdd(&cnt[c.w >> NBITS], 1);
    }
    __syncthreads();
    // exclusive prefix scan over NBUCK buckets: wave 0, lane-segment scan
    if (t < 64) {
        constexpr int SEG = (NBUCK + 63) / 64;  // 13
        int lo = t * SEG;
        int hi = min(lo + SEG, NBUCK);
        int s = 0;
        for (int i = lo; i < hi; ++i) {
            loff[i] = s;
            s += cnt[i];
        }
        int tot = s;
        int ex = tot;
#pragma unroll
        for (int off = 1; off < 64; off <<= 1) {
            int o = __shfl_up(ex, off, 64);
            if (t >= off) ex += o;
        }
        ex -= tot;  // exclusive prefix of this lane's segment total
        for (int i = lo; i < hi; ++i) loff[i] += ex;
    }
    __syncthreads();
    // global base alloc (one atomic per non-empty bucket)
    for (int i = t; i < NBUCK; i += PTHREADS) base[i] = cnt[i] ? atomicAdd(&cursor[i], cnt[i]) : 0;
    // pass B: re-read edges, place bucket-sorted into ed2 (no atomics)
    for (int i = t; i < n4; i += PTHREADS) {
        int4 r = r4[i];
        int4 c = c4[i];
        unsigned p0 = ((unsigned)r.x << 16) | (unsigned)c.x;
        unsigned p1 = ((unsigned)r.y << 16) | (unsigned)c.y;
        unsigned p2 = ((unsigned)r.z << 16) | (unsigned)c.z;
        unsigned p3 = ((unsigned)r.w << 16) | (unsigned)c.w;
        ed2[loff[c.x >> NBITS] + (int)tick[i * 4 + 0]] = p0;
        ed2[loff[c.y >> NBITS] + (int)tick[i * 4 + 1]] = p1;
        ed2[loff[c.z >> NBITS] + (int)tick[i * 4 + 2]] = p2;
        ed2[loff[c.w >> NBITS] + (int)tick[i * 4 + 3]] = p3;
    }
    __syncthreads();
    // coalesced write-out: consecutive s -> consecutive global addr per run
    for (int s = t; s < n; s += PTHREADS) {
        unsigned p = ed2[s];
        int bk = (int)(p & 0xffffu) >> NBITS;
        int pos = base[bk] + (s - loff[bk]);
        if (pos < CAP) bEdges[(size_t)bk * CAP + pos] = p;
    }
}

// Pass 2 (fused with mm1): per-bucket CSR (tile-grouped, 8-u16-aligned,
// zero-padded lists) + hs1 = pad64((x@W1)*dinv) + dlo[node] (deg in tiles 0-3).
// rowmeta = (globalStart<<7) | realDeg.
__global__ __launch_bounds__(CTHREADS) void bucket_csr_mm_kernel(const int* __restrict__ cursor,
                                                                 const unsigned* __restrict__ bEdges,
                                                                 const float* __restrict__ x,
                                                                 const float* __restrict__ W1,  // 50x50
                                                                 unsigned short* __restrict__ srcIdx,
                                                                 unsigned* __restrict__ rowmeta,
                                                                 unsigned char* __restrict__ dlo,
                                                                 float* __restrict__ dinv,
                                                                 uint2* __restrict__ Hs, int N) {
    __shared__ alignas(16) unsigned ed[CAP];             // 10.0 KB
    __shared__ alignas(16) unsigned short srcL[CAP];     //  5.0 KB
    __shared__ unsigned char tick[CAP];                  //  2.5 KB (rank in (l,tl))
    __shared__ int tdeg[BNODES * NTILE];                 //  2.0 KB
    __shared__ int toff[BNODES * NTILE];                 //  2.0 KB
    __shared__ int totPad;
    __shared__ float dinvL[BNODES];
    __shared__ float4 Ws4[50 * 16];                      // 12.5 KB (W1 pad 50x64)
    __shared__ float xs[BNODES][51];                     // 12.75 KB
    int b = blockIdx.x;
    int tx = threadIdx.x;
    int cnt = min(cursor[b], CAP);
    for (int i = tx; i < BNODES * NTILE; i += CTHREADS) tdeg[i] = 0;
    {  // zero srcL (pad slots -> safe index 0), vectorized: CAP/8 uint4 stores
        uint4* z4 = (uint4*)srcL;
        uint4 z = make_uint4(0u, 0u, 0u, 0u);
        for (int i = tx; i < (CAP >> 3); i += CTHREADS) z4[i] = z;
    }
    __syncthreads();
    // pass A: load edge segment (uint4 = 4 edges/instr), histogram + tickets
    const uint4* s4 = (const uint4*)(bEdges + (size_t)b * CAP);
    int cnt4 = cnt >> 2;
    for (int i = tx; i < cnt4; i += CTHREADS) {
        uint4 w = s4[i];
        ((uint4*)ed)[i] = w;
        unsigned pp[4] = {w.x, w.y, w.z, w.w};
#pragma unroll
        for (int u = 0; u < 4; ++u) {
            unsigned p = pp[u];
            int l = (int)(p & (BNODES - 1));
            int tl = (int)(p >> 16) / TROWS;  // 0..7
            tick[i * 4 + u] = (unsigned char)atomicAdd(&tdeg[l * NTILE + tl], 1);
        }
    }
    for (int i = cnt4 * 4 + tx; i < cnt; i += CTHREADS) {  // remainder (<4)
        unsigned p = bEdges[(size_t)b * CAP + i];
        ed[i] = p;
        int l = (int)(p & (BNODES - 1));
        int tl = (int)(p >> 16) / TROWS;
        tick[i] = (unsigned char)atomicAdd(&tdeg[l * NTILE + tl], 1);
    }
    for (int i = tx; i < 50 * 64; i += CTHREADS) {  // W1 -> LDS (zero-padded cols)
        int k = i >> 6;
        int c = i & 63;
        ((float*)Ws4)[i] = (c < 50) ? W1[k * 50 + c] : 0.f;
    }
    for (int i = tx; i < BNODES * 50; i += CTHREADS) {  // x rows -> LDS
        int l = i / 50;
        int k = i - l * 50;
        int node = b * BNODES + l;
        xs[l][k] = (node < N) ? x[(size_t)node * 50 + k] : 0.f;
    }
    __syncthreads();
    if (tx < BNODES) {  // wave 0: per-node totals, padded scan, offsets, meta
        int sd[NTILE];
        int d = 0;
#pragma unroll
        for (int u = 0; u < NTILE; ++u) {
            sd[u] = tdeg[tx * NTILE + u];
            d += sd[u];
        }
        int dl = sd[0] + sd[1] + sd[2] + sd[3];  // deg in tiles 0..3
        int dpad = (d + 7) & ~7;  // 8-ushort (16B) aligned segments
        int s = dpad;
#pragma unroll
        for (int off = 1; off < BNODES; off <<= 1) {
            int o = __shfl_up(s, off, 64);
            if (tx >= off) s += o;
        }
        int ex = s - dpad;
        int run = ex;
#pragma unroll
        for (int u = 0; u < NTILE; ++u) {
            toff[tx * NTILE + u] = run;
            run += sd[u];
        }
        if (tx == 63) totPad = min(s, CAP);
        float dvv = rsqrtf((float)d + 1.0f);  // +1 = self loop
        dinvL[tx] = dvv;
        int node = b * BNODES + tx;
        if (node < N) {
            unsigned st = (unsigned)(b * CAP + ex);
            rowmeta[node] = (st << 7) | (unsigned)d;
            dlo[node] = (unsigned char)dl;
            dinv[node] = dvv;
        }
    }
    __syncthreads();
    // pass B: place edges, atomic-free (ticket = rank within (l,tl) segment)
    for (int i = tx; i < cnt; i += CTHREADS) {
        unsigned p = ed[i];
        int l = (int)(p & (BNODES - 1));
        int tl = (int)(p >> 16) / TROWS;
        int pos = toff[l * NTILE + tl] + (int)tick[i];
        if (pos < CAP) srcL[pos] = (unsigned short)(p >> 16);
    }
    __syncthreads();
    int tot = totPad;  // multiple of 8; pad slots = 0 -> gather row 0, masked at use
    {
        const uint4* sl4 = (const uint4*)srcL;
        uint4* si4 = (uint4*)(srcIdx + (size_t)b * CAP);  // b*CAP u16 = 5120B, 16B-aligned
        for (int i = tx; i < (tot >> 3); i += CTHREADS) si4[i] = sl4[i];
    }
    // fused mm1: each thread emits 2 H4 outputs (nodes g, g+32)
    int q = tx & 15;
    int g = tx >> 4;  // 0..31
#pragma unroll
    for (int rep = 0; rep < 2; ++rep) {
        int l = g + rep * 32;
        float4 acc = make_float4(0.f, 0.f, 0.f, 0.f);
#pragma unroll
        for (int k = 0; k < 50; ++k) {
            float xv = xs[l][k];  // broadcast within 16-lane group
            float4 w = Ws4[k * 16 + q];
            acc.x = fmaf(xv, w.x, acc.x);
            acc.y = fmaf(xv, w.y, acc.y);
            acc.z = fmaf(xv, w.z, acc.z);
            acc.w = fmaf(xv, w.w, acc.w);
        }
        float dv = dinvL[l];
        acc.x *= dv;
        acc.y *= dv;
        acc.z *= dv;
        acc.w *= dv;
        int node = b * BNODES + l;
        if (node < N) Hs[(size_t)node * 16 + q] = f4_to_h4(acc).u;
    }
}

// Range gather, 8 lanes/node x uint4 (16B): accumulate rows srcIdx[jlo..jhi).
// Head batch (if jlo not 8-aligned) and tail batch are element-masked; masked
// elements clamp to row 0 so out-of-range loads stay inside the hot window.
// srcIdx loads are non-temporal (streaming; don't evict the row window).
__device__ inline void gather_range8(const unsigned short* __restrict__ srcIdx,
                                     const uint4* __restrict__ hs, int jlo, int jhi,
                                     int q, float4& A, float4& B) {
    if (jlo >= jhi) return;
    int j = jlo & ~7;
    if (j < jlo) {  // misaligned head: masked batch
        uint4 w = ntload_u4((const uint4*)(srcIdx + j));
        int r[8];
        unpack8(w, r);
#pragma unroll
        for (int u = 0; u < 8; ++u) {
            bool ok = (j + u >= jlo) && (j + u < jhi);
            H8 hv;
            hv.u = hs[(size_t)(ok ? r[u] : 0) * 8 + q];
            fma8(A, B, hv, ok ? 1.f : 0.f);
        }
        j += 8;
    }
    while (j + 8 <= jhi) {  // full batches
        uint4 w = ntload_u4((const uint4*)(srcIdx + j));
        int r[8];
        unpack8(w, r);
#pragma unroll
        for (int u = 0; u < 8; ++u) {
            H8 hv;
            hv.u = hs[(size_t)r[u] * 8 + q];
            add8(A, B, hv);
        }
        j += 8;
    }
    if (j < jhi) {  // tail: masked
        uint4 w = ntload_u4((const uint4*)(srcIdx + j));
        int r[8];
        unpack8(w, r);
#pragma unroll
        for (int u = 0; u < 8; ++u) {
            bool ok = (j + u < jhi);
            H8 hv;
            hv.u = hs[(size_t)(ok ? r[u] : 0) * 8 + q];
            fma8(A, B, hv, ok ? 1.f : 0.f);
        }
    }
}

// Phase A of an aggregation pass: self-loop (if node's row is in tiles 0-3)
// + tile-0..3 edges -> fp32 partial. Working set = hs rows 0..24999 (3.2MB,
// per-XCD-L2-resident). QMAX=7 skips the structurally-zero q=7 (layer 1).
template <int QMAX>
__global__ __launch_bounds__(256) void agg_phaseA_kernel(const unsigned* __restrict__ rowmeta,
                                                         const unsigned char* __restrict__ dlo,
                                                         const unsigned short* __restrict__ srcIdx,
                                                         const uint4* __restrict__ hs,
                                                         float4* __restrict__ part, int N) {
    int tid = blockIdx.x * blockDim.x + threadIdx.x;
    int node = tid >> 3;
    int q = tid & 7;
    if (node >= N || q >= QMAX) return;
    unsigned meta = rowmeta[node];
    int start = (int)(meta >> 7);
    int jmid = start + (int)dlo[node];
    float4 A = make_float4(0.f, 0.f, 0.f, 0.f), B = A;
    if (node < SPLIT_ROW) {  // self row lives in tiles 0-3: add first (R21 order)
        H8 s;
        s.u = hs[(size_t)node * 8 + q];
        add8(A, B, s);
    }
    gather_range8(srcIdx, hs, start, jmid, q, A, B);
    ntstore_f4(&part[(size_t)node * 16 + 2 * q], A);
    ntstore_f4(&part[(size_t)node * 16 + 2 * q + 1], B);
}

// Phase B of layer-1 pass: partial + (self if node>=25000) + tile-4..7 edges,
// then h1 = relu(dinv*acc+b1) -> LDS exchange -> hs2 = (h1@W2)*dinv -> out.
// Working set = hs rows 25000..49999. No early returns (barriers); OOB clamps.
template <int BC>
__global__ __launch_bounds__(256) void agg_mm_phaseB_kernel(const unsigned* __restrict__ rowmeta,
                                                            const unsigned char* __restrict__ dlo,
                                                            const unsigned short* __restrict__ srcIdx,
                                                            const uint4* __restrict__ hs,
                                                            const float4* __restrict__ part,
                                                            const float* __restrict__ dinv,
                                                            const float* __restrict__ b1,
                                                            const float* __restrict__ W2,  // 50x64
                                                            uint4* __restrict__ out, int N) {
    __shared__ float4 Ws4[50 * 16];  // W2 as float4 view (50x64)
    __shared__ float h1s[32][68];    // per-group h1 row, padded stride 68
    for (int i = threadIdx.x; i < 50 * 64; i += 256) ((float*)Ws4)[i] = W2[i];
    int tid = blockIdx.x * blockDim.x + threadIdx.x;
    int node = tid >> 3;
    int q = tid & 7;
    int g = threadIdx.x >> 3;  // group within block (0..31)
    int nodeC = min(node, N - 1);
    unsigned meta = rowmeta[nodeC];
    int start = (int)(meta >> 7);
    int d = (int)(meta & 127u);
    int jmid = start + (int)dlo[nodeC];
    float4 A = make_float4(0.f, 0.f, 0.f, 0.f), B = A;
    if (q < 7) {
        A = ntload_f4(&part[(size_t)nodeC * 16 + 2 * q]);
        B = ntload_f4(&part[(size_t)nodeC * 16 + 2 * q + 1]);
        if (nodeC >= SPLIT_ROW) {  // self row in tiles 4-7: add before B edges
            H8 s;
            s.u = hs[(size_t)nodeC * 8 + q];
            add8(A, B, s);
        }
        gather_range8(srcIdx, hs, jmid, start + d, q, A, B);
    }
    float dv = dinv[nodeC];
    int f = q * 8;
    float hv[8] = {A.x, A.y, A.z, A.w, B.x, B.y, B.z, B.w};
#pragma unroll
    for (int u = 0; u < 8; ++u) {
        float bb = (f + u < BC) ? b1[f + u] : 0.f;
        h1s[g][f + u] = fmaxf(dv * hv[u] + bb, 0.f);
    }
    __syncthreads();  // Ws4 staging + h1s exchange
    float4 aA = make_float4(0.f, 0.f, 0.f, 0.f), aB = aA;
#pragma unroll
    for (int k = 0; k < 50; ++k) {
        float xv = h1s[g][k];
        float4 wA = Ws4[k * 16 + 2 * q];
        float4 wB = Ws4[k * 16 + 2 * q + 1];
        aA.x = fmaf(xv, wA.x, aA.x);
        aA.y = fmaf(xv, wA.y, aA.y);
        aA.z = fmaf(xv, wA.z, aA.z);
        aA.w = fmaf(xv, wA.w, aA.w);
        aB.x = fmaf(xv, wB.x, aB.x);
        aB.y = fmaf(xv, wB.y, aB.y);
        aB.z = fmaf(xv, wB.z, aB.z);
        aB.w = fmaf(xv, wB.w, aB.w);
    }
    aA.x *= dv; aA.y *= dv; aA.z *= dv; aA.w *= dv;
    aB.x *= dv; aB.y *= dv; aB.z *= dv; aB.w *= dv;
    if (node < N) ntstore_u4(&out[(size_t)node * 8 + q], pack8(aA, aB));
}

// Phase B of layer-2 pass: partial + (self if node>=25000) + tile-4..7 edges,
// finalize z = dinv*acc + b2, pack fp16. No barriers -> early return OK.
template <int BC>
__global__ __launch_bounds__(256) void agg_phaseB_kernel(const unsigned* __restrict__ rowmeta,
                                                         const unsigned char* __restrict__ dlo,
                                                         const unsigned short* __restrict__ srcIdx,
                                                         const uint4* __restrict__ hs,
                                                         const float4* __restrict__ part,
                                                         const float* __restrict__ dinv,
                                                         const float* __restrict__ b,
                                                         uint4* __restrict__ out, int N) {
    int tid = blockIdx.x * blockDim.x + threadIdx.x;
    int node = tid >> 3;
    int q = tid & 7;
    if (node >= N) return;
    unsigned meta = rowmeta[node];
    int start = (int)(meta >> 7);
    int d = (int)(meta & 127u);
    int jmid = start + (int)dlo[node];
    float4 A = ntload_f4(&part[(size_t)node * 16 + 2 * q]);
    float4 B = ntload_f4(&part[(size_t)node * 16 + 2 * q + 1]);
    if (node >= SPLIT_ROW) {
        H8 s;
        s.u = hs[(size_t)node * 8 + q];
        add8(A, B, s);
    }
    gather_range8(srcIdx, hs, jmid, start + d, q, A, B);
    float dv = dinv[node];
    int f = q * 8;
    float hv[8] = {A.x, A.y, A.z, A.w, B.x, B.y, B.z, B.w};
    float o[8];
#pragma unroll
    for (int u = 0; u < 8; ++u) o[u] = dv * hv[u] + (f + u < BC ? b[f + u] : 0.f);
    ntstore_u4(&out[(size_t)node * 8 + q],
               pack8(make_float4(o[0], o[1], o[2], o[3]), make_float4(o[4], o[5], o[6], o[7])));
}

// 8 lanes per edge, 8 edges per wave; lane loads uint4 (8 fp16) of each row.
__global__ __launch_bounds__(256) void decode_kernel(const int* __restrict__ pos,
                                                     const int* __restrict__ neg, int Ep, int En,
                                                     const uint4* __restrict__ z4,
                                                     float* __restrict__ logits) {
    int tid = blockIdx.x * blockDim.x + threadIdx.x;
    int e = tid >> 3;
    int q = tid & 7;
    int Etot = Ep + En;
    if (e >= Etot) return;
    int a, bn;
    if (e < Ep) {
        a = pos[e];
        bn = pos[Ep + e];
    } else {
        int t = e - Ep;
        a = neg[t];
        bn = neg[En + t];
    }
    uint4 ua = z4[(size_t)a * 8 + q];
    uint4 ub = z4[(size_t)bn * 8 + q];
    float v = hdot2(ua.x, ub.x) + hdot2(ua.y, ub.y) + hdot2(ua.z, ub.z) + hdot2(ua.w, ub.w);
    v += __shfl_xor(v, 1, 64);
    v += __shfl_xor(v, 2, 64);
    v += __shfl_xor(v, 4, 64);
    if (q == 0) logits[e] = v;
}

extern "C" void kernel_launch(void* const* d_in, const int* in_sizes, int n_in,
                              void* d_out, int out_size, void* d_ws, size_t ws_size,
                              hipStream_t stream) {
    const float* x = (const float*)d_in[0];
    const int* train = (const int*)d_in[1];
    const int* pos = (const int*)d_in[2];
    const int* neg = (const int*)d_in[3];
    const float* W1 = (const float*)d_in[4];
    const float* b1 = (const float*)d_in[5];
    const float* W2 = (const float*)d_in[6];
    const float* b2 = (const float*)d_in[7];
    float* logits = (float*)d_out;

    const int FIN = 50;
    const int N = in_sizes[0] / FIN;  // 50000
    const int E = in_sizes[1] / 2;    // 1600000
    const int Ep = in_sizes[2] / 2;   // 200000
    const int En = in_sizes[3] / 2;   // 200000

    const int* t_row = train;      // sources
    const int* t_col = train + E;  // targets

    // ws layout (no overlays; ws is ~268MB):
    //   dinv[N] f32 | buf0[N*64] fp16 | buf1[N*64] fp16 | rowmeta[N] u32 |
    //   cursor[NBUCK] i32 | srcIdx[NBUCK*CAP] u16 (16B-aligned) |
    //   bEdges[NBUCK*CAP] u32 (16B-aligned) | dlo[N] u8 |
    //   fpart[N*16] float4 (16B-aligned, 12.8MB)
    float* dinv = (float*)d_ws;
    __half* buf0 = (__half*)(dinv + N);
    __half* buf1 = buf0 + (size_t)N * 64;
    unsigned* rowmeta = (unsigned*)(buf1 + (size_t)N * 64);
    int* cursor = (int*)(rowmeta + N);
    uintptr_t sp = (uintptr_t)(cursor + NBUCK);
    sp = (sp + 15) & ~(uintptr_t)15;  // 16B align for uint4 loads
    unsigned short* srcIdx = (unsigned short*)sp;
    uintptr_t bp = (uintptr_t)(srcIdx + (size_t)NBUCK * CAP);
    bp = (bp + 15) & ~(uintptr_t)15;
    unsigned* bEdges = (unsigned*)bp;
    unsigned char* dlo = (unsigned char*)(bEdges + (size_t)NBUCK * CAP);
    uintptr_t fp = (uintptr_t)(dlo + N);
    fp = (fp + 15) & ~(uintptr_t)15;
    float4* fpart = (float4*)fp;

    (void)hipMemsetAsync(cursor, 0, (size_t)NBUCK * sizeof(int), stream);

    // CSR build + fused mm1 (shared by both layers)
    partition_kernel<<<(E + CHUNK - 1) / CHUNK, PTHREADS, 0, stream>>>((const int4*)t_row,
                                                                       (const int4*)t_col, E,
                                                                       cursor, bEdges);
    bucket_csr_mm_kernel<<<NBUCK, CTHREADS, 0, stream>>>(cursor, bEdges, x, W1, srcIdx, rowmeta,
                                                         dlo, dinv, (uint2*)buf0, N);

    const int AGB = (N * 8 + 255) / 256;  // 1563 blocks

    // layer 1: phase A (tiles 0-3 window) -> fp32 partial; phase B (tiles 4-7)
    // + relu/b1 + mm2 + dinv -> hs2 -> buf1
    agg_phaseA_kernel<7><<<AGB, 256, 0, stream>>>(rowmeta, dlo, srcIdx, (const uint4*)buf0,
                                                  fpart, N);
    agg_mm_phaseB_kernel<50><<<AGB, 256, 0, stream>>>(rowmeta, dlo, srcIdx, (const uint4*)buf0,
                                                      fpart, dinv, b1, W2, (uint4*)buf1, N);
    // layer 2: same two-phase split; z -> buf0
    agg_phaseA_kernel<8><<<AGB, 256, 0, stream>>>(rowmeta, dlo, srcIdx, (const uint4*)buf1,
                                                  fpart, N);
    agg_phaseB_kernel<64><<<AGB, 256, 0, stream>>>(rowmeta, dlo, srcIdx, (const uint4*)buf1,
                                                   fpart, dinv, b2, (uint4*)buf0, N);
    // decode from z = buf0 (8 lanes/edge)
    decode_kernel<<<((Ep + En) * 8 + 255) / 256, 256, 0, stream>>>(pos, neg, Ep, En,
                                                                   (const uint4*)buf0, logits);
}

// Round 12
// 190.186 us; speedup vs baseline: 1.1684x; 1.1684x over previous
//
#include <hip/hip_runtime.h>
#include <hip/hip_bf16.h>
#include <hip/hip_fp16.h>

// GCN link-prediction: 2x GCNConv + dot decoder. N=50000, F_in=50, H=50, D=64,
// E_train=1.6M, Ep=En=200k.
//
// R25 -> R26. Locality program CLOSED: three independent falsifications
// (R23 lane-split +13us, R24 plane-loops +6us, R25 launch-boundary +25us).
// Revised model: agg gathers are fabric/L3-BW bound (~205MB/pass / ~6.8TB/s
// ~= 30us/pass, matching R22's probe exactly); L2 does not retain the row
// window under this access pattern. Aggs accepted at ~60us combined.
// R26 = revert to R21's best-known agg/decode path (197.5us config) +
// SINGLE CHANGE: bucket_csr_mm LDS diet. R18 profile showed it latency-bound
// (Occ 19%, VALU 10%, HBM 5%) with 48.75KB LDS capping residency at 3
// blocks/CU. Drop ed[CAP] (pass B re-reads bEdges from L2) and xs[][]
// (mm1 reads x direct; 16 lanes read same addr -> HW broadcast, same
// traffic). LDS 48.75 -> 24.3KB -> 4 blocks/CU = 32 waves/CU (wave-limit
// max, +33%), and pass A sheds its LDS edge-store work.
// Carried: R21 sorted-coalesced partition, R20 idx-prefetch gather, R19
// ticketed bucket @512, R18 8-lane uint4 gathers + q=7 skip, R17 CHUNK 6144 /
// NTILE 8 / fused kernels / fp16 buffers / 8-lane decode.

constexpr int N_NODES = 50000;
constexpr int NBITS = 6;                          // 64 nodes per bucket
constexpr int BNODES = 1 << NBITS;                // 64
constexpr int NBUCK = (N_NODES + BNODES - 1) / BNODES;  // 782
constexpr int CAP = 2560;     // per-bucket capacity incl. 8-align pad (6.4 sigma)
constexpr int CHUNK = 6144;   // edges per partition block (261 blocks)
constexpr int PTHREADS = 512; // partition block size (8 waves)
constexpr int CTHREADS = 512; // bucket_csr_mm block size (8 waves)
constexpr int NTILE = 8;
constexpr int TROWS = 6250;   // rows per tile (8 tiles cover 50000)

union H4 {  // 4 fp16 = 8 bytes = one uint2 load/store
    uint2 u;
    __half2 h[2];
};

union H8 {  // 8 fp16 = 16 bytes = one uint4 load/store
    uint4 u;
    __half2 h[4];
};

__device__ inline H4 f4_to_h4(float4 v) {
    H4 r;
    r.h[0] = __floats2half2_rn(v.x, v.y);
    r.h[1] = __floats2half2_rn(v.z, v.w);
    return r;
}

__device__ inline uint4 pack8(float4 A, float4 B) {
    H8 r;
    r.h[0] = __floats2half2_rn(A.x, A.y);
    r.h[1] = __floats2half2_rn(A.z, A.w);
    r.h[2] = __floats2half2_rn(B.x, B.y);
    r.h[3] = __floats2half2_rn(B.z, B.w);
    return r.u;
}

__device__ inline void unpack8(uint4 w, int* r) {
    r[0] = (int)(w.x & 0xffffu);  r[1] = (int)(w.x >> 16);
    r[2] = (int)(w.y & 0xffffu);  r[3] = (int)(w.y >> 16);
    r[4] = (int)(w.z & 0xffffu);  r[5] = (int)(w.z >> 16);
    r[6] = (int)(w.w & 0xffffu);  r[7] = (int)(w.w >> 16);
}

__device__ inline void add8(float4& A, float4& B, H8 v) {
    float2 g0 = __half22float2(v.h[0]);
    float2 g1 = __half22float2(v.h[1]);
    float2 g2 = __half22float2(v.h[2]);
    float2 g3 = __half22float2(v.h[3]);
    A.x += g0.x; A.y += g0.y; A.z += g1.x; A.w += g1.y;
    B.x += g2.x; B.y += g2.y; B.z += g3.x; B.w += g3.y;
}

__device__ inline void fma8(float4& A, float4& B, H8 v, float m) {
    float2 g0 = __half22float2(v.h[0]);
    float2 g1 = __half22float2(v.h[1]);
    float2 g2 = __half22float2(v.h[2]);
    float2 g3 = __half22float2(v.h[3]);
    A.x = fmaf(m, g0.x, A.x); A.y = fmaf(m, g0.y, A.y);
    A.z = fmaf(m, g1.x, A.z); A.w = fmaf(m, g1.y, A.w);
    B.x = fmaf(m, g2.x, B.x); B.y = fmaf(m, g2.y, B.y);
    B.z = fmaf(m, g3.x, B.z); B.w = fmaf(m, g3.y, B.w);
}

__device__ inline float hdot2(unsigned ua, unsigned ub) {
    __half2 ha = *(__half2*)&ua;
    __half2 hb = *(__half2*)&ub;
    float2 fa = __half22float2(ha);
    float2 fb = __half22float2(hb);
    return fa.x * fb.x + fa.y * fb.y;
}

// Pass 1: bucket edges by target, block-locally SORTED by bucket before the
// global write so consecutive lanes write consecutive addresses per bucket
// run (coalesced). Packed edge = (row<<16)|col (both < 65536).
__global__ __launch_bounds__(PTHREADS) void partition_kernel(const int4* __restrict__ row4,
                                                             const int4* __restrict__ col4, int E,
                                                             int* __restrict__ cursor,
                                                             unsigned* __restrict__ bEdges) {
    __shared__ unsigned ed2[CHUNK];        // 24 KB: bucket-sorted edges
    __shared__ unsigned char tick[CHUNK];  //  6 KB: rank within (block,bucket)
    __shared__ int cnt[NBUCK];             // 3.1 KB
    __shared__ int loff[NBUCK];            // 3.1 KB: local sorted segment start
    __shared__ int base[NBUCK];            // 3.1 KB: global segment start
    int t = threadIdx.x;
    int e0 = blockIdx.x * CHUNK;
    int n = min(CHUNK, E - e0);  // multiple of 4
    int n4 = n >> 2;
    for (int i = t; i < NBUCK; i += PTHREADS) cnt[i] = 0;
    __syncthreads();
    const int4* r4 = row4 + (e0 >> 2);
    const int4* c4 = col4 + (e0 >> 2);
    // pass A: histogram + tickets (cols only; edges re-read L2-hot in pass B)
    for (int i = t; i < n4; i += PTHREADS) {
        int4 c = c4[i];
        tick[i * 4 + 0] = (unsigned char)atomicAdd(&cnt[c.x >> NBITS], 1);
        tick[i * 4 + 1] = (unsigned char)atomicAdd(&cnt[c.y >> NBITS], 1);
        tick[i * 4 + 2] = (unsigned char)atomicAdd(&cnt[c.z >> NBITS], 1);
        tick[i * 4 + 3] = (unsigned char)atomicAdd(&cnt[c.w >> NBITS], 1);
    }
    __syncthreads();
    // exclusive prefix scan over NBUCK buckets: wave 0, lane-segment scan
    if (t < 64) {
        constexpr int SEG = (NBUCK + 63) / 64;  // 13
        int lo = t * SEG;
        int hi = min(lo + SEG, NBUCK);
        int s = 0;
        for (int i = lo; i < hi; ++i) {
            loff[i] = s;
            s += cnt[i];
        }
        int tot = s;
        int ex = tot;
#pragma unroll
        for (int off = 1; off < 64; off <<= 1) {
            int o = __shfl_up(ex, off, 64);
            if (t >= off) ex += o;
        }
        ex -= tot;  // exclusive prefix of this lane's segment total
        for (int i = lo; i < hi; ++i) loff[i] += ex;
    }
    __syncthreads();
    // global base alloc (one atomic per non-empty bucket)
    for (int i = t; i < NBUCK; i += PTHREADS) base[i] = cnt[i] ? atomicAdd(&cursor[i], cnt[i]) : 0;
    // pass B: re-read edges, place bucket-sorted into ed2 (no atomics)
    for (int i = t; i < n4; i += PTHREADS) {
        int4 r = r4[i];
        int4 c = c4[i];
        unsigned p0 = ((unsigned)r.x << 16) | (unsigned)c.x;
        unsigned p1 = ((unsigned)r.y << 16) | (unsigned)c.y;
        unsigned p2 = ((unsigned)r.z << 16) | (unsigned)c.z;
        unsigned p3 = ((unsigned)r.w << 16) | (unsigned)c.w;
        ed2[loff[c.x >> NBITS] + (int)tick[i * 4 + 0]] = p0;
        ed2[loff[c.y >> NBITS] + (int)tick[i * 4 + 1]] = p1;
        ed2[loff[c.z >> NBITS] + (int)tick[i * 4 + 2]] = p2;
        ed2[loff[c.w >> NBITS] + (int)tick[i * 4 + 3]] = p3;
    }
    __syncthreads();
    // coalesced write-out: consecutive s -> consecutive global addr per run
    for (int s = t; s < n; s += PTHREADS) {
        unsigned p = ed2[s];
        int bk = (int)(p & 0xffffu) >> NBITS;
        int pos = base[bk] + (s - loff[bk]);
        if (pos < CAP) bEdges[(size_t)bk * CAP + pos] = p;
    }
}

// Pass 2 (fused with mm1): per-bucket CSR (tile-grouped, 8-u16-aligned,
// zero-padded lists) + hs1 = pad64((x@W1)*dinv) for the bucket's 64 nodes.
// rowmeta = (globalStart<<7) | realDeg.
// R26 LDS diet: no ed[] (bEdges re-read from L2 in pass B), no xs[] (mm1
// reads x direct, 16-lane broadcast). LDS ~24.3KB -> 4 blocks/CU (32 waves).
__global__ __launch_bounds__(CTHREADS) void bucket_csr_mm_kernel(const int* __restrict__ cursor,
                                                                 const unsigned* __restrict__ bEdges,
                                                                 const float* __restrict__ x,
                                                                 const float* __restrict__ W1,  // 50x50
                                                                 unsigned short* __restrict__ srcIdx,
                                                                 unsigned* __restrict__ rowmeta,
                                                                 float* __restrict__ dinv,
                                                                 uint2* __restrict__ Hs, int N) {
    __shared__ alignas(16) unsigned short srcL[CAP];     //  5.0 KB
    __shared__ unsigned char tick[CAP];                  //  2.5 KB (rank in (l,tl))
    __shared__ int tdeg[BNODES * NTILE];                 //  2.0 KB
    __shared__ int toff[BNODES * NTILE];                 //  2.0 KB
    __shared__ int totPad;
    __shared__ float dinvL[BNODES];                      // 256 B
    __shared__ float4 Ws4[50 * 16];                      // 12.5 KB (W1 pad 50x64)
    int b = blockIdx.x;
    int tx = threadIdx.x;
    int cnt = min(cursor[b], CAP);
    for (int i = tx; i < BNODES * NTILE; i += CTHREADS) tdeg[i] = 0;
    {  // zero srcL (pad slots -> safe index 0), vectorized: CAP/8 uint4 stores
        uint4* z4 = (uint4*)srcL;
        uint4 z = make_uint4(0u, 0u, 0u, 0u);
        for (int i = tx; i < (CAP >> 3); i += CTHREADS) z4[i] = z;
    }
    __syncthreads();
    // pass A: read edge segment (uint4 = 4 edges/instr), histogram + tickets
    const uint4* s4 = (const uint4*)(bEdges + (size_t)b * CAP);
    int cnt4 = cnt >> 2;
    for (int i = tx; i < cnt4; i += CTHREADS) {
        uint4 w = s4[i];
        unsigned pp[4] = {w.x, w.y, w.z, w.w};
#pragma unroll
        for (int u = 0; u < 4; ++u) {
            unsigned p = pp[u];
            int l = (int)(p & (BNODES - 1));
            int tl = (int)(p >> 16) / TROWS;  // 0..7
            tick[i * 4 + u] = (unsigned char)atomicAdd(&tdeg[l * NTILE + tl], 1);
        }
    }
    for (int i = cnt4 * 4 + tx; i < cnt; i += CTHREADS) {  // remainder (<4)
        unsigned p = bEdges[(size_t)b * CAP + i];
        int l = (int)(p & (BNODES - 1));
        int tl = (int)(p >> 16) / TROWS;
        tick[i] = (unsigned char)atomicAdd(&tdeg[l * NTILE + tl], 1);
    }
    for (int i = tx; i < 50 * 64; i += CTHREADS) {  // W1 -> LDS (zero-padded cols)
        int k = i >> 6;
        int c = i & 63;
        ((float*)Ws4)[i] = (c < 50) ? W1[k * 50 + c] : 0.f;
    }
    __syncthreads();
    if (tx < BNODES) {  // wave 0: per-node totals, padded scan, offsets, meta
        int sd[NTILE];
        int d = 0;
#pragma unroll
        for (int u = 0; u < NTILE; ++u) {
            sd[u] = tdeg[tx * NTILE + u];
            d += sd[u];
        }
        int dpad = (d + 7) & ~7;  // 8-ushort (16B) aligned segments
        int s = dpad;
#pragma unroll
        for (int off = 1; off < BNODES; off <<= 1) {
            int o = __shfl_up(s, off, 64);
            if (tx >= off) s += o;
        }
        int ex = s - dpad;
        int run = ex;
#pragma unroll
        for (int u = 0; u < NTILE; ++u) {
            toff[tx * NTILE + u] = run;
            run += sd[u];
        }
        if (tx == 63) totPad = min(s, CAP);
        float dvv = rsqrtf((float)d + 1.0f);  // +1 = self loop
        dinvL[tx] = dvv;
        int node = b * BNODES + tx;
        if (node < N) {
            unsigned st = (unsigned)(b * CAP + ex);
            rowmeta[node] = (st << 7) | (unsigned)d;
            dinv[node] = dvv;
        }
    }
    __syncthreads();
    // pass B: re-read edges (L2-hot), place atomic-free (ticket = rank)
    for (int i = tx; i < cnt4; i += CTHREADS) {
        uint4 w = s4[i];
        unsigned pp[4] = {w.x, w.y, w.z, w.w};
#pragma unroll
        for (int u = 0; u < 4; ++u) {
            unsigned p = pp[u];
            int l = (int)(p & (BNODES - 1));
            int tl = (int)(p >> 16) / TROWS;
            int pos = toff[l * NTILE + tl] + (int)tick[i * 4 + u];
            if (pos < CAP) srcL[pos] = (unsigned short)(p >> 16);
        }
    }
    for (int i = cnt4 * 4 + tx; i < cnt; i += CTHREADS) {  // remainder
        unsigned p = bEdges[(size_t)b * CAP + i];
        int l = (int)(p & (BNODES - 1));
        int tl = (int)(p >> 16) / TROWS;
        int pos = toff[l * NTILE + tl] + (int)tick[i];
        if (pos < CAP) srcL[pos] = (unsigned short)(p >> 16);
    }
    __syncthreads();
    int tot = totPad;  // multiple of 8; pad slots = 0 -> gather row 0, masked at use
    {
        const uint4* sl4 = (const uint4*)srcL;
        uint4* si4 = (uint4*)(srcIdx + (size_t)b * CAP);  // b*CAP u16 = 5120B, 16B-aligned
        for (int i = tx; i < (tot >> 3); i += CTHREADS) si4[i] = sl4[i];
    }
    // fused mm1: each thread emits 2 H4 outputs (nodes g, g+32); x read direct
    // (16 lanes/group read the same address -> HW broadcast, 1 req/group).
    int q = tx & 15;
    int g = tx >> 4;  // 0..31
#pragma unroll
    for (int rep = 0; rep < 2; ++rep) {
        int l = g + rep * 32;
        int node = b * BNODES + l;
        const float* xr = x + (size_t)min(node, N - 1) * 50;
        float4 acc = make_float4(0.f, 0.f, 0.f, 0.f);
#pragma unroll
        for (int k = 0; k < 50; ++k) {
            float xv = xr[k];  // broadcast within 16-lane group
            float4 w = Ws4[k * 16 + q];
            acc.x = fmaf(xv, w.x, acc.x);
            acc.y = fmaf(xv, w.y, acc.y);
            acc.z = fmaf(xv, w.z, acc.z);
            acc.w = fmaf(xv, w.w, acc.w);
        }
        float dv = dinvL[l];
        acc.x *= dv;
        acc.y *= dv;
        acc.z *= dv;
        acc.w *= dv;
        if (node < N) Hs[(size_t)node * 16 + q] = f4_to_h4(acc).u;
    }
}

// Gather core, 8 lanes/node x uint4 (16B), idx-prefetch pipelined: the uint4
// index word for batch j+1 is loaded while batch j's rows load/accumulate.
// Prefetch guarded by (j+8 < end) -> stays inside this node's 8-padded
// segment (no OOB).
__device__ inline void gather_sum8(const unsigned short* __restrict__ srcIdx,
                                   const uint4* __restrict__ hs, int node, int q,
                                   unsigned meta, float4& A, float4& B) {
    int start = (int)(meta >> 7);
    int d = (int)(meta & 127u);
    int end = start + d;
    H8 t;
    t.u = hs[(size_t)node * 8 + q];  // self loop
    {
        float2 g0 = __half22float2(t.h[0]);
        float2 g1 = __half22float2(t.h[1]);
        float2 g2 = __half22float2(t.h[2]);
        float2 g3 = __half22float2(t.h[3]);
        A = make_float4(g0.x, g0.y, g1.x, g1.y);
        B = make_float4(g2.x, g2.y, g3.x, g3.y);
    }
    if (d == 0) return;
    int j = start;
    uint4 w = *(const uint4*)(srcIdx + j);  // batch-0 idx (16B-aligned, 8-pad)
    while (j + 8 <= end) {
        uint4 wc = w;
        if (j + 8 < end) w = *(const uint4*)(srcIdx + j + 8);  // prefetch next
        int r[8];
        unpack8(wc, r);
#pragma unroll
        for (int u = 0; u < 8; ++u) {
            H8 hv;
            hv.u = hs[(size_t)r[u] * 8 + q];
            add8(A, B, hv);
        }
        j += 8;
    }
    if (j < end) {  // masked remainder batch; idx word already prefetched in w
        int r[8];
        unpack8(w, r);
#pragma unroll
        for (int u = 0; u < 8; ++u) {
            float m = (j + u < end) ? 1.f : 0.f;
            H8 hv;
            hv.u = hs[(size_t)r[u] * 8 + q];
            fma8(A, B, hv, m);
        }
    }
}

// Fused layer-1 tail + layer-2 matmul: agg -> h1 = relu(dinv*acc+b1) ->
// (LDS row exchange) -> hs2 = (h1 @ W2)*dinv -> buf out.
// 8 lanes/node; q=7 (features 56..63) is structurally zero in hs1 -> skip its
// gather entirely. No early returns (barrier safety); OOB nodes clamp reads
// and skip the store.
template <int BC>
__global__ __launch_bounds__(256) void agg_mm_kernel(const unsigned* __restrict__ rowmeta,
                                                     const unsigned short* __restrict__ srcIdx,
                                                     const uint4* __restrict__ hs,
                                                     const float* __restrict__ dinv,
                                                     const float* __restrict__ b1,
                                                     const float* __restrict__ W2,  // 50x64
                                                     uint4* __restrict__ out, int N) {
    __shared__ float4 Ws4[50 * 16];  // W2 as float4 view (50x64)
    __shared__ float h1s[32][68];    // per-group h1 row, padded stride 68
    for (int i = threadIdx.x; i < 50 * 64; i += 256) ((float*)Ws4)[i] = W2[i];
    int tid = blockIdx.x * blockDim.x + threadIdx.x;
    int node = tid >> 3;
    int q = tid & 7;
    int g = threadIdx.x >> 3;  // group within block (0..31)
    int nodeC = min(node, N - 1);
    float4 A = make_float4(0.f, 0.f, 0.f, 0.f), B = A;
    if (q < 7) gather_sum8(srcIdx, hs, nodeC, q, rowmeta[nodeC], A, B);
    float dv = dinv[nodeC];
    int f = q * 8;
    float hv[8] = {A.x, A.y, A.z, A.w, B.x, B.y, B.z, B.w};
#pragma unroll
    for (int u = 0; u < 8; ++u) {
        float bb = (f + u < BC) ? b1[f + u] : 0.f;
        h1s[g][f + u] = fmaxf(dv * hv[u] + bb, 0.f);
    }
    __syncthreads();  // also covers the Ws4 staging above
    float4 aA = make_float4(0.f, 0.f, 0.f, 0.f), aB = aA;
#pragma unroll
    for (int k = 0; k < 50; ++k) {
        float xv = h1s[g][k];
        float4 wA = Ws4[k * 16 + 2 * q];
        float4 wB = Ws4[k * 16 + 2 * q + 1];
        aA.x = fmaf(xv, wA.x, aA.x);
        aA.y = fmaf(xv, wA.y, aA.y);
        aA.z = fmaf(xv, wA.z, aA.z);
        aA.w = fmaf(xv, wA.w, aA.w);
        aB.x = fmaf(xv, wB.x, aB.x);
        aB.y = fmaf(xv, wB.y, aB.y);
        aB.z = fmaf(xv, wB.z, aB.z);
        aB.w = fmaf(xv, wB.w, aB.w);
    }
    aA.x *= dv; aA.y *= dv; aA.z *= dv; aA.w *= dv;
    aB.x *= dv; aB.y *= dv; aB.z *= dv; aB.w *= dv;
    if (node < N) out[(size_t)node * 8 + q] = pack8(aA, aB);
}

// Plain final aggregation (layer 2): agg -> z = dinv*acc + b2 (no relu).
template <int BC>
__global__ __launch_bounds__(256) void agg_kernel(const unsigned* __restrict__ rowmeta,
                                                  const unsigned short* __restrict__ srcIdx,
                                                  const uint4* __restrict__ hs,
                                                  const float* __restrict__ dinv,
                                                  const float* __restrict__ b,
                                                  uint4* __restrict__ out, int N) {
    int tid = blockIdx.x * blockDim.x + threadIdx.x;
    int node = tid >> 3;
    int q = tid & 7;
    if (node >= N) return;
    float4 A, B;
    gather_sum8(srcIdx, hs, node, q, rowmeta[node], A, B);
    float dv = dinv[node];
    int f = q * 8;
    float hv[8] = {A.x, A.y, A.z, A.w, B.x, B.y, B.z, B.w};
    float o[8];
#pragma unroll
    for (int u = 0; u < 8; ++u) o[u] = dv * hv[u] + (f + u < BC ? b[f + u] : 0.f);
    out[(size_t)node * 8 + q] =
        pack8(make_float4(o[0], o[1], o[2], o[3]), make_float4(o[4], o[5], o[6], o[7]));
}

// 8 lanes per edge, 8 edges per wave; lane loads uint4 (8 fp16) of each row.
__global__ __launch_bounds__(256) void decode_kernel(const int* __restrict__ pos,
                                                     const int* __restrict__ neg, int Ep, int En,
                                                     const uint4* __restrict__ z4,
                                                     float* __restrict__ logits) {
    int tid = blockIdx.x * blockDim.x + threadIdx.x;
    int e = tid >> 3;
    int q = tid & 7;
    int Etot = Ep + En;
    if (e >= Etot) return;
    int a, bn;
    if (e < Ep) {
        a = pos[e];
        bn = pos[Ep + e];
    } else {
        int t = e - Ep;
        a = neg[t];
        bn = neg[En + t];
    }
    uint4 ua = z4[(size_t)a * 8 + q];
    uint4 ub = z4[(size_t)bn * 8 + q];
    float v = hdot2(ua.x, ub.x) + hdot2(ua.y, ub.y) + hdot2(ua.z, ub.z) + hdot2(ua.w, ub.w);
    v += __shfl_xor(v, 1, 64);
    v += __shfl_xor(v, 2, 64);
    v += __shfl_xor(v, 4, 64);
    if (q == 0) logits[e] = v;
}

extern "C" void kernel_launch(void* const* d_in, const int* in_sizes, int n_in,
                              void* d_out, int out_size, void* d_ws, size_t ws_size,
                              hipStream_t stream) {
    const float* x = (const float*)d_in[0];
    const int* train = (const int*)d_in[1];
    const int* pos = (const int*)d_in[2];
    const int* neg = (const int*)d_in[3];
    const float* W1 = (const float*)d_in[4];
    const float* b1 = (const float*)d_in[5];
    const float* W2 = (const float*)d_in[6];
    const float* b2 = (const float*)d_in[7];
    float* logits = (float*)d_out;

    const int FIN = 50;
    const int N = in_sizes[0] / FIN;  // 50000
    const int E = in_sizes[1] / 2;    // 1600000
    const int Ep = in_sizes[2] / 2;   // 200000
    const int En = in_sizes[3] / 2;   // 200000

    const int* t_row = train;      // sources
    const int* t_col = train + E;  // targets

    // ws layout (no overlays; ws is ~268MB):
    //   dinv[N] f32 | buf0[N*64] fp16 | buf1[N*64] fp16 | rowmeta[N] u32 |
    //   cursor[NBUCK] i32 | srcIdx[NBUCK*CAP] u16 (16B-aligned) |
    //   bEdges[NBUCK*CAP] u32 (16B-aligned)
    float* dinv = (float*)d_ws;
    __half* buf0 = (__half*)(dinv + N);
    __half* buf1 = buf0 + (size_t)N * 64;
    unsigned* rowmeta = (unsigned*)(buf1 + (size_t)N * 64);
    int* cursor = (int*)(rowmeta + N);
    uintptr_t sp = (uintptr_t)(cursor + NBUCK);
    sp = (sp + 15) & ~(uintptr_t)15;  // 16B align for uint4 loads
    unsigned short* srcIdx = (unsigned short*)sp;
    uintptr_t bp = (uintptr_t)(srcIdx + (size_t)NBUCK * CAP);
    bp = (bp + 15) & ~(uintptr_t)15;
    unsigned* bEdges = (unsigned*)bp;

    (void)hipMemsetAsync(cursor, 0, (size_t)NBUCK * sizeof(int), stream);

    // CSR build + fused mm1 (shared by both layers)
    partition_kernel<<<(E + CHUNK - 1) / CHUNK, PTHREADS, 0, stream>>>((const int4*)t_row,
                                                                       (const int4*)t_col, E,
                                                                       cursor, bEdges);
    bucket_csr_mm_kernel<<<NBUCK, CTHREADS, 0, stream>>>(cursor, bEdges, x, W1, srcIdx, rowmeta,
                                                         dinv, (uint2*)buf0, N);

    const int AGB = (N * 8 + 255) / 256;  // 1563 blocks (last half-idle, clamped)

    // fused: agg1 + relu/b1 + mm2 + dinv -> hs2 -> buf1
    agg_mm_kernel<50><<<AGB, 256, 0, stream>>>(rowmeta, srcIdx, (const uint4*)buf0, dinv, b1, W2,
                                               (uint4*)buf1, N);
    // layer 2 aggregation: z -> buf0
    agg_kernel<64><<<AGB, 256, 0, stream>>>(rowmeta, srcIdx, (const uint4*)buf1, dinv, b2,
                                            (uint4*)buf0, N);
    // decode from z = buf0 (8 lanes/edge)
    decode_kernel<<<((Ep + En) * 8 + 255) / 256, 256, 0, stream>>>(pos, neg, Ep, En,
                                                                   (const uint4*)buf0, logits);
}

// Round 13
// 182.842 us; speedup vs baseline: 1.2153x; 1.0402x over previous
//
#include <hip/hip_runtime.h>
#include <hip/hip_bf16.h>
#include <hip/hip_fp16.h>

// GCN link-prediction: 2x GCNConv + dot decoder. N=50000, F_in=50, H=50, D=64,
// E_train=1.6M, Ep=En=200k.
//
// R26 -> R27 (two independent levers, separate kernels):
//  (1) partition_kernel 512 -> 1024 threads (261 blocks ~ 1/CU): 8 -> 16
//      waves/CU for a pure streaming+LDS-atomic kernel. Same CHUNK/locality.
//      (Same under-occupancy disease R26 cured in bucket_csr_mm: -7.3us.)
//  (2) hs1 rows packed at 7xuint4 = 112B (features 0..55; 50..55 stored
//      zeros). The q=7 slot-skip avoided DEMANDING bytes 112..127 but TCC
//      lines are 128B -> whole row fetched anyway. Packing makes demand =
//      fetch: layer-1 gather traffic -12.5% (~25MB ~= 4us at the measured
//      fabric ceiling). STRIDE template on the proven gather core; layer-2 z
//      and decode stay stride-8.
// Both order-preserving per feature -> bit-identical numerics.
// Model context: aggs are fabric/L3-BW bound (~60us combined, R22 probe;
// locality program closed after R23/R24/R25 falsifications). R26 LDS diet
// brought bucket_csr_mm to 4 blocks/CU (190.2us total, best).
// Carried: R21 sorted-coalesced partition, R20 idx-prefetch gather, R19
// ticketed bucket @512, R18 8-lane uint4 gathers + q=7 skip, R17 CHUNK 6144 /
// NTILE 8 / fused kernels / fp16 buffers / 8-lane decode.

constexpr int N_NODES = 50000;
constexpr int NBITS = 6;                          // 64 nodes per bucket
constexpr int BNODES = 1 << NBITS;                // 64
constexpr int NBUCK = (N_NODES + BNODES - 1) / BNODES;  // 782
constexpr int CAP = 2560;     // per-bucket capacity incl. 8-align pad (6.4 sigma)
constexpr int CHUNK = 6144;   // edges per partition block (261 blocks)
constexpr int PTHREADS = 1024; // partition block size (16 waves -> 16/CU)
constexpr int CTHREADS = 512;  // bucket_csr_mm block size (8 waves)
constexpr int NTILE = 8;
constexpr int TROWS = 6250;   // rows per tile (8 tiles cover 50000)
constexpr int H1STRIDE = 7;   // hs1 row = 7 uint4 = 112B (features 0..55)

union H4 {  // 4 fp16 = 8 bytes = one uint2 load/store
    uint2 u;
    __half2 h[2];
};

union H8 {  // 8 fp16 = 16 bytes = one uint4 load/store
    uint4 u;
    __half2 h[4];
};

__device__ inline H4 f4_to_h4(float4 v) {
    H4 r;
    r.h[0] = __floats2half2_rn(v.x, v.y);
    r.h[1] = __floats2half2_rn(v.z, v.w);
    return r;
}

__device__ inline uint4 pack8(float4 A, float4 B) {
    H8 r;
    r.h[0] = __floats2half2_rn(A.x, A.y);
    r.h[1] = __floats2half2_rn(A.z, A.w);
    r.h[2] = __floats2half2_rn(B.x, B.y);
    r.h[3] = __floats2half2_rn(B.z, B.w);
    return r.u;
}

__device__ inline void unpack8(uint4 w, int* r) {
    r[0] = (int)(w.x & 0xffffu);  r[1] = (int)(w.x >> 16);
    r[2] = (int)(w.y & 0xffffu);  r[3] = (int)(w.y >> 16);
    r[4] = (int)(w.z & 0xffffu);  r[5] = (int)(w.z >> 16);
    r[6] = (int)(w.w & 0xffffu);  r[7] = (int)(w.w >> 16);
}

__device__ inline void add8(float4& A, float4& B, H8 v) {
    float2 g0 = __half22float2(v.h[0]);
    float2 g1 = __half22float2(v.h[1]);
    float2 g2 = __half22float2(v.h[2]);
    float2 g3 = __half22float2(v.h[3]);
    A.x += g0.x; A.y += g0.y; A.z += g1.x; A.w += g1.y;
    B.x += g2.x; B.y += g2.y; B.z += g3.x; B.w += g3.y;
}

__device__ inline void fma8(float4& A, float4& B, H8 v, float m) {
    float2 g0 = __half22float2(v.h[0]);
    float2 g1 = __half22float2(v.h[1]);
    float2 g2 = __half22float2(v.h[2]);
    float2 g3 = __half22float2(v.h[3]);
    A.x = fmaf(m, g0.x, A.x); A.y = fmaf(m, g0.y, A.y);
    A.z = fmaf(m, g1.x, A.z); A.w = fmaf(m, g1.y, A.w);
    B.x = fmaf(m, g2.x, B.x); B.y = fmaf(m, g2.y, B.y);
    B.z = fmaf(m, g3.x, B.z); B.w = fmaf(m, g3.y, B.w);
}

__device__ inline float hdot2(unsigned ua, unsigned ub) {
    __half2 ha = *(__half2*)&ua;
    __half2 hb = *(__half2*)&ub;
    float2 fa = __half22float2(ha);
    float2 fb = __half22float2(hb);
    return fa.x * fb.x + fa.y * fb.y;
}

// Pass 1: bucket edges by target, block-locally SORTED by bucket before the
// global write so consecutive lanes write consecutive addresses per bucket
// run (coalesced). Packed edge = (row<<16)|col (both < 65536).
__global__ __launch_bounds__(PTHREADS) void partition_kernel(const int4* __restrict__ row4,
                                                             const int4* __restrict__ col4, int E,
                                                             int* __restrict__ cursor,
                                                             unsigned* __restrict__ bEdges) {
    __shared__ unsigned ed2[CHUNK];        // 24 KB: bucket-sorted edges
    __shared__ unsigned char tick[CHUNK];  //  6 KB: rank within (block,bucket)
    __shared__ int cnt[NBUCK];             // 3.1 KB
    __shared__ int loff[NBUCK];            // 3.1 KB: local sorted segment start
    __shared__ int base[NBUCK];            // 3.1 KB: global segment start
    int t = threadIdx.x;
    int e0 = blockIdx.x * CHUNK;
    int n = min(CHUNK, E - e0);  // multiple of 4
    int n4 = n >> 2;
    for (int i = t; i < NBUCK; i += PTHREADS) cnt[i] = 0;
    __syncthreads();
    const int4* r4 = row4 + (e0 >> 2);
    const int4* c4 = col4 + (e0 >> 2);
    // pass A: histogram + tickets (cols only; edges re-read L2-hot in pass B)
    for (int i = t; i < n4; i += PTHREADS) {
        int4 c = c4[i];
        tick[i * 4 + 0] = (unsigned char)atomicAdd(&cnt[c.x >> NBITS], 1);
        tick[i * 4 + 1] = (unsigned char)atomicAdd(&cnt[c.y >> NBITS], 1);
        tick[i * 4 + 2] = (unsigned char)atomicAdd(&cnt[c.z >> NBITS], 1);
        tick[i * 4 + 3] = (unsigned char)atomicAdd(&cnt[c.w >> NBITS], 1);
    }
    __syncthreads();
    // exclusive prefix scan over NBUCK buckets: wave 0, lane-segment scan
    if (t < 64) {
        constexpr int SEG = (NBUCK + 63) / 64;  // 13
        int lo = t * SEG;
        int hi = min(lo + SEG, NBUCK);
        int s = 0;
        for (int i = lo; i < hi; ++i) {
            loff[i] = s;
            s += cnt[i];
        }
        int tot = s;
        int ex = tot;
#pragma unroll
        for (int off = 1; off < 64; off <<= 1) {
            int o = __shfl_up(ex, off, 64);
            if (t >= off) ex += o;
        }
        ex -= tot;  // exclusive prefix of this lane's segment total
        for (int i = lo; i < hi; ++i) loff[i] += ex;
    }
    __syncthreads();
    // global base alloc (one atomic per non-empty bucket)
    for (int i = t; i < NBUCK; i += PTHREADS) base[i] = cnt[i] ? atomicAdd(&cursor[i], cnt[i]) : 0;
    // pass B: re-read edges, place bucket-sorted into ed2 (no atomics)
    for (int i = t; i < n4; i += PTHREADS) {
        int4 r = r4[i];
        int4 c = c4[i];
        unsigned p0 = ((unsigned)r.x << 16) | (unsigned)c.x;
        unsigned p1 = ((unsigned)r.y << 16) | (unsigned)c.y;
        unsigned p2 = ((unsigned)r.z << 16) | (unsigned)c.z;
        unsigned p3 = ((unsigned)r.w << 16) | (unsigned)c.w;
        ed2[loff[c.x >> NBITS] + (int)tick[i * 4 + 0]] = p0;
        ed2[loff[c.y >> NBITS] + (int)tick[i * 4 + 1]] = p1;
        ed2[loff[c.z >> NBITS] + (int)tick[i * 4 + 2]] = p2;
        ed2[loff[c.w >> NBITS] + (int)tick[i * 4 + 3]] = p3;
    }
    __syncthreads();
    // coalesced write-out: consecutive s -> consecutive global addr per run
    for (int s = t; s < n; s += PTHREADS) {
        unsigned p = ed2[s];
        int bk = (int)(p & 0xffffu) >> NBITS;
        int pos = base[bk] + (s - loff[bk]);
        if (pos < CAP) bEdges[(size_t)bk * CAP + pos] = p;
    }
}

// Pass 2 (fused with mm1): per-bucket CSR (tile-grouped, 8-u16-aligned,
// zero-padded lists) + hs1 = pack112((x@W1)*dinv) for the bucket's 64 nodes.
// rowmeta = (globalStart<<7) | realDeg.
// R26 LDS diet: no ed[] (bEdges re-read from L2 in pass B), no xs[] (mm1
// reads x direct, 16-lane broadcast). LDS ~24.3KB -> 4 blocks/CU (32 waves).
// R27: hs1 rows packed at 14 uint2 = 112B (features 0..55).
__global__ __launch_bounds__(CTHREADS) void bucket_csr_mm_kernel(const int* __restrict__ cursor,
                                                                 const unsigned* __restrict__ bEdges,
                                                                 const float* __restrict__ x,
                                                                 const float* __restrict__ W1,  // 50x50
                                                                 unsigned short* __restrict__ srcIdx,
                                                                 unsigned* __restrict__ rowmeta,
                                                                 float* __restrict__ dinv,
                                                                 uint2* __restrict__ Hs, int N) {
    __shared__ alignas(16) unsigned short srcL[CAP];     //  5.0 KB
    __shared__ unsigned char tick[CAP];                  //  2.5 KB (rank in (l,tl))
    __shared__ int tdeg[BNODES * NTILE];                 //  2.0 KB
    __shared__ int toff[BNODES * NTILE];                 //  2.0 KB
    __shared__ int totPad;
    __shared__ float dinvL[BNODES];                      // 256 B
    __shared__ float4 Ws4[50 * 16];                      // 12.5 KB (W1 pad 50x64)
    int b = blockIdx.x;
    int tx = threadIdx.x;
    int cnt = min(cursor[b], CAP);
    for (int i = tx; i < BNODES * NTILE; i += CTHREADS) tdeg[i] = 0;
    {  // zero srcL (pad slots -> safe index 0), vectorized: CAP/8 uint4 stores
        uint4* z4 = (uint4*)srcL;
        uint4 z = make_uint4(0u, 0u, 0u, 0u);
        for (int i = tx; i < (CAP >> 3); i += CTHREADS) z4[i] = z;
    }
    __syncthreads();
    // pass A: read edge segment (uint4 = 4 edges/instr), histogram + tickets
    const uint4* s4 = (const uint4*)(bEdges + (size_t)b * CAP);
    int cnt4 = cnt >> 2;
    for (int i = tx; i < cnt4; i += CTHREADS) {
        uint4 w = s4[i];
        unsigned pp[4] = {w.x, w.y, w.z, w.w};
#pragma unroll
        for (int u = 0; u < 4; ++u) {
            unsigned p = pp[u];
            int l = (int)(p & (BNODES - 1));
            int tl = (int)(p >> 16) / TROWS;  // 0..7
            tick[i * 4 + u] = (unsigned char)atomicAdd(&tdeg[l * NTILE + tl], 1);
        }
    }
    for (int i = cnt4 * 4 + tx; i < cnt; i += CTHREADS) {  // remainder (<4)
        unsigned p = bEdges[(size_t)b * CAP + i];
        int l = (int)(p & (BNODES - 1));
        int tl = (int)(p >> 16) / TROWS;
        tick[i] = (unsigned char)atomicAdd(&tdeg[l * NTILE + tl], 1);
    }
    for (int i = tx; i < 50 * 64; i += CTHREADS) {  // W1 -> LDS (zero-padded cols)
        int k = i >> 6;
        int c = i & 63;
        ((float*)Ws4)[i] = (c < 50) ? W1[k * 50 + c] : 0.f;
    }
    __syncthreads();
    if (tx < BNODES) {  // wave 0: per-node totals, padded scan, offsets, meta
        int sd[NTILE];
        int d = 0;
#pragma unroll
        for (int u = 0; u < NTILE; ++u) {
            sd[u] = tdeg[tx * NTILE + u];
            d += sd[u];
        }
        int dpad = (d + 7) & ~7;  // 8-ushort (16B) aligned segments
        int s = dpad;
#pragma unroll
        for (int off = 1; off < BNODES; off <<= 1) {
            int o = __shfl_up(s, off, 64);
            if (tx >= off) s += o;
        }
        int ex = s - dpad;
        int run = ex;
#pragma unroll
        for (int u = 0; u < NTILE; ++u) {
            toff[tx * NTILE + u] = run;
            run += sd[u];
        }
        if (tx == 63) totPad = min(s, CAP);
        float dvv = rsqrtf((float)d + 1.0f);  // +1 = self loop
        dinvL[tx] = dvv;
        int node = b * BNODES + tx;
        if (node < N) {
            unsigned st = (unsigned)(b * CAP + ex);
            rowmeta[node] = (st << 7) | (unsigned)d;
            dinv[node] = dvv;
        }
    }
    __syncthreads();
    // pass B: re-read edges (L2-hot), place atomic-free (ticket = rank)
    for (int i = tx; i < cnt4; i += CTHREADS) {
        uint4 w = s4[i];
        unsigned pp[4] = {w.x, w.y, w.z, w.w};
#pragma unroll
        for (int u = 0; u < 4; ++u) {
            unsigned p = pp[u];
            int l = (int)(p & (BNODES - 1));
            int tl = (int)(p >> 16) / TROWS;
            int pos = toff[l * NTILE + tl] + (int)tick[i * 4 + u];
            if (pos < CAP) srcL[pos] = (unsigned short)(p >> 16);
        }
    }
    for (int i = cnt4 * 4 + tx; i < cnt; i += CTHREADS) {  // remainder
        unsigned p = bEdges[(size_t)b * CAP + i];
        int l = (int)(p & (BNODES - 1));
        int tl = (int)(p >> 16) / TROWS;
        int pos = toff[l * NTILE + tl] + (int)tick[i];
        if (pos < CAP) srcL[pos] = (unsigned short)(p >> 16);
    }
    __syncthreads();
    int tot = totPad;  // multiple of 8; pad slots = 0 -> gather row 0, masked at use
    {
        const uint4* sl4 = (const uint4*)srcL;
        uint4* si4 = (uint4*)(srcIdx + (size_t)b * CAP);  // b*CAP u16 = 5120B, 16B-aligned
        for (int i = tx; i < (tot >> 3); i += CTHREADS) si4[i] = sl4[i];
    }
    // fused mm1: each thread emits 2 H4 outputs (nodes g, g+32); x read direct
    // (16 lanes/group read the same address -> HW broadcast, 1 req/group).
    // Packed write: only q<14 slots stored (112B/row, features 0..55).
    int q = tx & 15;
    int g = tx >> 4;  // 0..31
#pragma unroll
    for (int rep = 0; rep < 2; ++rep) {
        int l = g + rep * 32;
        int node = b * BNODES + l;
        const float* xr = x + (size_t)min(node, N - 1) * 50;
        float4 acc = make_float4(0.f, 0.f, 0.f, 0.f);
#pragma unroll
        for (int k = 0; k < 50; ++k) {
            float xv = xr[k];  // broadcast within 16-lane group
            float4 w = Ws4[k * 16 + q];
            acc.x = fmaf(xv, w.x, acc.x);
            acc.y = fmaf(xv, w.y, acc.y);
            acc.z = fmaf(xv, w.z, acc.z);
            acc.w = fmaf(xv, w.w, acc.w);
        }
        float dv = dinvL[l];
        acc.x *= dv;
        acc.y *= dv;
        acc.z *= dv;
        acc.w *= dv;
        if (node < N && q < 2 * H1STRIDE) Hs[(size_t)node * (2 * H1STRIDE) + q] = f4_to_h4(acc).u;
    }
}

// Gather core, 8 lanes/node x uint4 (16B), idx-prefetch pipelined; row stride
// in uint4s is a template param (7 = packed 112B hs1, 8 = 128B hs2/z).
// The uint4 index word for batch j+1 is loaded while batch j's rows
// load/accumulate. Prefetch guarded by (j+8 < end) -> stays in-segment.
template <int STRIDE>
__device__ inline void gather_sum8(const unsigned short* __restrict__ srcIdx,
                                   const uint4* __restrict__ hs, int node, int q,
                                   unsigned meta, float4& A, float4& B) {
    int start = (int)(meta >> 7);
    int d = (int)(meta & 127u);
    int end = start + d;
    H8 t;
    t.u = hs[(size_t)node * STRIDE + q];  // self loop
    {
        float2 g0 = __half22float2(t.h[0]);
        float2 g1 = __half22float2(t.h[1]);
        float2 g2 = __half22float2(t.h[2]);
        float2 g3 = __half22float2(t.h[3]);
        A = make_float4(g0.x, g0.y, g1.x, g1.y);
        B = make_float4(g2.x, g2.y, g3.x, g3.y);
    }
    if (d == 0) return;
    int j = start;
    uint4 w = *(const uint4*)(srcIdx + j);  // batch-0 idx (16B-aligned, 8-pad)
    while (j + 8 <= end) {
        uint4 wc = w;
        if (j + 8 < end) w = *(const uint4*)(srcIdx + j + 8);  // prefetch next
        int r[8];
        unpack8(wc, r);
#pragma unroll
        for (int u = 0; u < 8; ++u) {
            H8 hv;
            hv.u = hs[(size_t)r[u] * STRIDE + q];
            add8(A, B, hv);
        }
        j += 8;
    }
    if (j < end) {  // masked remainder batch; idx word already prefetched in w
        int r[8];
        unpack8(w, r);
#pragma unroll
        for (int u = 0; u < 8; ++u) {
            float m = (j + u < end) ? 1.f : 0.f;
            H8 hv;
            hv.u = hs[(size_t)r[u] * STRIDE + q];
            fma8(A, B, hv, m);
        }
    }
}

// Fused layer-1 tail + layer-2 matmul: agg -> h1 = relu(dinv*acc+b1) ->
// (LDS row exchange) -> hs2 = (h1 @ W2)*dinv -> buf out.
// 8 lanes/node; STRIDE=7 packed hs1 (q=7 lane idle: features 56..63 gone).
// No early returns (barrier safety); OOB nodes clamp reads, skip stores.
template <int BC>
__global__ __launch_bounds__(256) void agg_mm_kernel(const unsigned* __restrict__ rowmeta,
                                                     const unsigned short* __restrict__ srcIdx,
                                                     const uint4* __restrict__ hs,
                                                     const float* __restrict__ dinv,
                                                     const float* __restrict__ b1,
                                                     const float* __restrict__ W2,  // 50x64
                                                     uint4* __restrict__ out, int N) {
    __shared__ float4 Ws4[50 * 16];  // W2 as float4 view (50x64)
    __shared__ float h1s[32][68];    // per-group h1 row, padded stride 68
    for (int i = threadIdx.x; i < 50 * 64; i += 256) ((float*)Ws4)[i] = W2[i];
    int tid = blockIdx.x * blockDim.x + threadIdx.x;
    int node = tid >> 3;
    int q = tid & 7;
    int g = threadIdx.x >> 3;  // group within block (0..31)
    int nodeC = min(node, N - 1);
    float4 A = make_float4(0.f, 0.f, 0.f, 0.f), B = A;
    if (q < 7) gather_sum8<H1STRIDE>(srcIdx, hs, nodeC, q, rowmeta[nodeC], A, B);
    float dv = dinv[nodeC];
    int f = q * 8;
    float hv[8] = {A.x, A.y, A.z, A.w, B.x, B.y, B.z, B.w};
#pragma unroll
    for (int u = 0; u < 8; ++u) {
        float bb = (f + u < BC) ? b1[f + u] : 0.f;
        h1s[g][f + u] = fmaxf(dv * hv[u] + bb, 0.f);
    }
    __syncthreads();  // also covers the Ws4 staging above
    float4 aA = make_float4(0.f, 0.f, 0.f, 0.f), aB = aA;
#pragma unroll
    for (int k = 0; k < 50; ++k) {
        float xv = h1s[g][k];
        float4 wA = Ws4[k * 16 + 2 * q];
        float4 wB = Ws4[k * 16 + 2 * q + 1];
        aA.x = fmaf(xv, wA.x, aA.x);
        aA.y = fmaf(xv, wA.y, aA.y);
        aA.z = fmaf(xv, wA.z, aA.z);
        aA.w = fmaf(xv, wA.w, aA.w);
        aB.x = fmaf(xv, wB.x, aB.x);
        aB.y = fmaf(xv, wB.y, aB.y);
        aB.z = fmaf(xv, wB.z, aB.z);
        aB.w = fmaf(xv, wB.w, aB.w);
    }
    aA.x *= dv; aA.y *= dv; aA.z *= dv; aA.w *= dv;
    aB.x *= dv; aB.y *= dv; aB.z *= dv; aB.w *= dv;
    if (node < N) out[(size_t)node * 8 + q] = pack8(aA, aB);
}

// Plain final aggregation (layer 2): agg -> z = dinv*acc + b2 (no relu).
template <int BC>
__global__ __launch_bounds__(256) void agg_kernel(const unsigned* __restrict__ rowmeta,
                                                  const unsigned short* __restrict__ srcIdx,
                                                  const uint4* __restrict__ hs,
                                                  const float* __restrict__ dinv,
                                                  const float* __restrict__ b,
                                                  uint4* __restrict__ out, int N) {
    int tid = blockIdx.x * blockDim.x + threadIdx.x;
    int node = tid >> 3;
    int q = tid & 7;
    if (node >= N) return;
    float4 A, B;
    gather_sum8<8>(srcIdx, hs, node, q, rowmeta[node], A, B);
    float dv = dinv[node];
    int f = q * 8;
    float hv[8] = {A.x, A.y, A.z, A.w, B.x, B.y, B.z, B.w};
    float o[8];
#pragma unroll
    for (int u = 0; u < 8; ++u) o[u] = dv * hv[u] + (f + u < BC ? b[f + u] : 0.f);
    out[(size_t)node * 8 + q] =
        pack8(make_float4(o[0], o[1], o[2], o[3]), make_float4(o[4], o[5], o[6], o[7]));
}

// 8 lanes per edge, 8 edges per wave; lane loads uint4 (8 fp16) of each row.
__global__ __launch_bounds__(256) void decode_kernel(const int* __restrict__ pos,
                                                     const int* __restrict__ neg, int Ep, int En,
                                                     const uint4* __restrict__ z4,
                                                     float* __restrict__ logits) {
    int tid = blockIdx.x * blockDim.x + threadIdx.x;
    int e = tid >> 3;
    int q = tid & 7;
    int Etot = Ep + En;
    if (e >= Etot) return;
    int a, bn;
    if (e < Ep) {
        a = pos[e];
        bn = pos[Ep + e];
    } else {
        int t = e - Ep;
        a = neg[t];
        bn = neg[En + t];
    }
    uint4 ua = z4[(size_t)a * 8 + q];
    uint4 ub = z4[(size_t)bn * 8 + q];
    float v = hdot2(ua.x, ub.x) + hdot2(ua.y, ub.y) + hdot2(ua.z, ub.z) + hdot2(ua.w, ub.w);
    v += __shfl_xor(v, 1, 64);
    v += __shfl_xor(v, 2, 64);
    v += __shfl_xor(v, 4, 64);
    if (q == 0) logits[e] = v;
}

extern "C" void kernel_launch(void* const* d_in, const int* in_sizes, int n_in,
                              void* d_out, int out_size, void* d_ws, size_t ws_size,
                              hipStream_t stream) {
    const float* x = (const float*)d_in[0];
    const int* train = (const int*)d_in[1];
    const int* pos = (const int*)d_in[2];
    const int* neg = (const int*)d_in[3];
    const float* W1 = (const float*)d_in[4];
    const float* b1 = (const float*)d_in[5];
    const float* W2 = (const float*)d_in[6];
    const float* b2 = (const float*)d_in[7];
    float* logits = (float*)d_out;

    const int FIN = 50;
    const int N = in_sizes[0] / FIN;  // 50000
    const int E = in_sizes[1] / 2;    // 1600000
    const int Ep = in_sizes[2] / 2;   // 200000
    const int En = in_sizes[3] / 2;   // 200000

    const int* t_row = train;      // sources
    const int* t_col = train + E;  // targets

    // ws layout (no overlays; ws is ~268MB):
    //   dinv[N] f32 | buf0[N*64] fp16 (hs1 packed 112B/row, later z 128B/row) |
    //   buf1[N*64] fp16 | rowmeta[N] u32 | cursor[NBUCK] i32 |
    //   srcIdx[NBUCK*CAP] u16 (16B-aligned) | bEdges[NBUCK*CAP] u32 (16B-aligned)
    float* dinv = (float*)d_ws;
    __half* buf0 = (__half*)(dinv + N);
    __half* buf1 = buf0 + (size_t)N * 64;
    unsigned* rowmeta = (unsigned*)(buf1 + (size_t)N * 64);
    int* cursor = (int*)(rowmeta + N);
    uintptr_t sp = (uintptr_t)(cursor + NBUCK);
    sp = (sp + 15) & ~(uintptr_t)15;  // 16B align for uint4 loads
    unsigned short* srcIdx = (unsigned short*)sp;
    uintptr_t bp = (uintptr_t)(srcIdx + (size_t)NBUCK * CAP);
    bp = (bp + 15) & ~(uintptr_t)15;
    unsigned* bEdges = (unsigned*)bp;

    (void)hipMemsetAsync(cursor, 0, (size_t)NBUCK * sizeof(int), stream);

    // CSR build + fused mm1 (shared by both layers)
    partition_kernel<<<(E + CHUNK - 1) / CHUNK, PTHREADS, 0, stream>>>((const int4*)t_row,
                                                                       (const int4*)t_col, E,
                                                                       cursor, bEdges);
    bucket_csr_mm_kernel<<<NBUCK, CTHREADS, 0, stream>>>(cursor, bEdges, x, W1, srcIdx, rowmeta,
                                                         dinv, (uint2*)buf0, N);

    const int AGB = (N * 8 + 255) / 256;  // 1563 blocks (last half-idle, clamped)

    // fused: agg1 (packed 112B hs1) + relu/b1 + mm2 + dinv -> hs2 -> buf1
    agg_mm_kernel<50><<<AGB, 256, 0, stream>>>(rowmeta, srcIdx, (const uint4*)buf0, dinv, b1, W2,
                                               (uint4*)buf1, N);
    // layer 2 aggregation: z -> buf0 (stride-8 128B rows)
    agg_kernel<64><<<AGB, 256, 0, stream>>>(rowmeta, srcIdx, (const uint4*)buf1, dinv, b2,
                                            (uint4*)buf0, N);
    // decode from z = buf0 (8 lanes/edge)
    decode_kernel<<<((Ep + En) * 8 + 255) / 256, 256, 0, stream>>>(pos, neg, Ep, En,
                                                                   (const uint4*)buf0, logits);
}